// Round 2
// baseline (290.793 us; speedup 1.0000x reference)
//
#include <hip/hip_runtime.h>

// Soft VQ encoding, fused bf16-MFMA implementation. Round 2.
//   X:(8,16384,128) fp32, C:(128,128) fp32, S:(128) fp32 -> E:(8,128,128) fp32
// 3 kernels on stream:
//   1. cprep<<<1,256>>>: C fp32->bf16 into ws (L2-resident matmul1 A-operand),
//      ST[k] = {S[k], S[k]*C2[k]} fp32 into ws.
//   2. vq_main<<<1024,256>>>, __launch_bounds__(256,4): grid = 8 b x 128 blk/b,
//      TT=2 chunks of 64 rows each. LDS ~40KB -> 4 blocks/CU, 16 waves/CU
//      (2x round-1 occupancy). matmul1 A-frags read from global bf16 C (L2 hit)
//      instead of LDS. Epilogue: bf16 PARTIAL stores to private ws slice
//      (replaces 8.4M contended fp32 atomics of round 1).
//   3. vq_reduce<<<128,256>>>: sum 128 bf16 partials per (b,cw,d) in fp32,
//      write d_out (fully overwrites -> no memset needed).
// fp32 kept for: X2, C2, S, softmax, count*C. bf16 in matmuls + partials.

#define NN   16384
#define ND   128
#define NK   128
#define NC   64        // rows per chunk
#define TT   2         // chunks per block
#define BPB  128       // blocks per batch (grid = 8*BPB = 1024)
#define XTP  72        // X^T LDS row stride, 144B
#define ATP  72        // A^T LDS row stride, 144B

typedef __bf16 bf16x8 __attribute__((ext_vector_type(8)));
typedef float  f32x4  __attribute__((ext_vector_type(4)));

__device__ __forceinline__ unsigned short f2bf(float x) {
    unsigned int u = __float_as_uint(x);
    u = (u + 0x7fffu + ((u >> 16) & 1u)) >> 16;   // round-to-nearest-even
    return (unsigned short)u;
}
__device__ __forceinline__ float bf2f(unsigned short u) {
    return __uint_as_float(((unsigned int)u) << 16);
}

// ---------------- kernel 1: C prep ----------------
__global__ void cprep(const float* __restrict__ Cg, const float* __restrict__ Sg,
                      unsigned short* __restrict__ Cbf, float2* __restrict__ ST)
{
    const int t = threadIdx.x;        // 256 threads
    const int r = t >> 1;             // row 0..127
    const int h = t & 1;              // half-row
    const float* row = Cg + r * ND + h * 64;
    unsigned short* orow = Cbf + r * ND + h * 64;
    float ss = 0.f;
    #pragma unroll
    for (int i = 0; i < 16; ++i) {
        float4 v = reinterpret_cast<const float4*>(row)[i];
        ss += v.x*v.x + v.y*v.y + v.z*v.z + v.w*v.w;
        ushort4 hh;
        hh.x = f2bf(v.x); hh.y = f2bf(v.y); hh.z = f2bf(v.z); hh.w = f2bf(v.w);
        reinterpret_cast<ushort4*>(orow)[i] = hh;
    }
    ss += __shfl_xor(ss, 1);          // combine the two half-rows (same wave)
    if (h == 0) {
        float s = Sg[r];
        ST[r] = make_float2(s, s * ss);
    }
}

// ---------------- kernel 2: fused main ----------------
__global__ __launch_bounds__(256, 4) void vq_main(
    const float* __restrict__ Xg, const float* __restrict__ Cg,
    const unsigned short* __restrict__ Cbf, const float2* __restrict__ STg,
    unsigned short* __restrict__ Pg)
{
    __shared__ __align__(16) unsigned short sXT[ND * XTP];   // 18432 B
    __shared__ __align__(16) unsigned short sAt[NK * ATP];   // 18432 B
    __shared__ __align__(16) float2 sST[NK];                 // 1 KB
    __shared__ __align__(16) float  sCntW[4][NK];            // 2 KB

    const int tid  = threadIdx.x;
    const int lane = tid & 63;
    const int wave = tid >> 6;
    const int l15  = lane & 15;
    const int quad = lane >> 4;
    const int bid  = blockIdx.x;
    const int b    = bid >> 7;        // batch
    const int bg   = bid & (BPB - 1); // block-in-batch

    if (tid < NK) sST[tid] = STg[tid];
    // (barrier (A) of chunk 0 orders sST before first softmax use)

    f32x4 eacc[2][8];
    #pragma unroll
    for (int i = 0; i < 2; ++i)
        #pragma unroll
        for (int j = 0; j < 8; ++j)
            eacc[i][j] = (f32x4){0.f, 0.f, 0.f, 0.f};
    float cnt[8][4];
    #pragma unroll
    for (int mt = 0; mt < 8; ++mt)
        #pragma unroll
        for (int r = 0; r < 4; ++r) cnt[mt][r] = 0.f;

    const float* Xb = Xg + (size_t)b * (NN * ND);
    const int rloc = wave * 16 + l15;   // chunk-local row this lane stages

    #pragma unroll 1
    for (int t = 0; t < TT; ++t) {
        const int chunk = bg * TT + t;
        const float* rp = Xb + (size_t)(chunk * NC + rloc) * ND;

        // ---- load this wave's 16 rows as matmul1 B-fragments; fp32 X2 ----
        union CU { unsigned short u[8]; bf16x8 v; };
        CU cu[4];
        float x2 = 0.f;
        #pragma unroll
        for (int ks = 0; ks < 4; ++ks) {
            float4 va = *reinterpret_cast<const float4*>(rp + ks * 32 + quad * 8);
            float4 vb = *reinterpret_cast<const float4*>(rp + ks * 32 + quad * 8 + 4);
            x2 += va.x*va.x + va.y*va.y + va.z*va.z + va.w*va.w;
            x2 += vb.x*vb.x + vb.y*vb.y + vb.z*vb.z + vb.w*vb.w;
            cu[ks].u[0] = f2bf(va.x); cu[ks].u[1] = f2bf(va.y);
            cu[ks].u[2] = f2bf(va.z); cu[ks].u[3] = f2bf(va.w);
            cu[ks].u[4] = f2bf(vb.x); cu[ks].u[5] = f2bf(vb.y);
            cu[ks].u[6] = f2bf(vb.z); cu[ks].u[7] = f2bf(vb.w);
        }
        x2 += __shfl_xor(x2, 16);
        x2 += __shfl_xor(x2, 32);       // full X2 of row (chunk*64 + rloc)

        __syncthreads();                // (A) prev chunk's matmul2 reads done

        // ---- scatter X^T (swizzled to dodge bank conflicts) ----
        #pragma unroll
        for (int ks = 0; ks < 4; ++ks) {
            #pragma unroll
            for (int j = 0; j < 8; ++j) {
                int d  = ks * 32 + quad * 8 + j;
                int rs = rloc ^ (((d >> 3) & 3) << 3);
                sXT[d * XTP + rs] = cu[ks].u[j];
            }
        }

        // ---- matmul1: DT[cw][n] = C x X^T (A-frags from global bf16 C, L2) ----
        f32x4 dacc[8];
        #pragma unroll
        for (int mt = 0; mt < 8; ++mt) {
            f32x4 acc = (f32x4){0.f, 0.f, 0.f, 0.f};
            #pragma unroll
            for (int ks = 0; ks < 4; ++ks) {
                bf16x8 af = *reinterpret_cast<const bf16x8*>(
                    &Cbf[(mt * 16 + l15) * ND + ks * 32 + quad * 8]);
                acc = __builtin_amdgcn_mfma_f32_16x16x32_bf16(af, cu[ks].v, acc, 0, 0, 0);
            }
            dacc[mt] = acc;
        }

        // ---- softmax over cw (lane's column n = rloc) ----
        float mx = -3.0e38f;
        #pragma unroll
        for (int mt = 0; mt < 8; ++mt) {
            #pragma unroll
            for (int r = 0; r < 4; ++r) {
                float2 st = sST[mt * 16 + quad * 4 + r];
                float dv = st.x * fmaf(-2.f, dacc[mt][r], x2) + st.y;  // S*(X2-2XC)+S*C2
                dacc[mt][r] = dv;
                mx = fmaxf(mx, dv);
            }
        }
        mx = fmaxf(mx, __shfl_xor(mx, 16));
        mx = fmaxf(mx, __shfl_xor(mx, 32));
        float ls = 0.f;
        #pragma unroll
        for (int mt = 0; mt < 8; ++mt) {
            #pragma unroll
            for (int r = 0; r < 4; ++r) {
                float e = __expf(dacc[mt][r] - mx);
                dacc[mt][r] = e;
                ls += e;
            }
        }
        ls += __shfl_xor(ls, 16);
        ls += __shfl_xor(ls, 32);
        const float inv = 1.0f / ls;

        // ---- A -> LDS (A-operand layout: rows=cw, cols=n), count accumulate ----
        #pragma unroll
        for (int mt = 0; mt < 8; ++mt) {
            #pragma unroll
            for (int r = 0; r < 4; ++r) {
                float a = dacc[mt][r] * inv;
                cnt[mt][r] += a;
                sAt[(mt * 16 + quad * 4 + r) * ATP + rloc] = f2bf(a);
            }
        }

        __syncthreads();                // (B) X^T and A^T visible to all waves

        // ---- matmul2: E[cw][d] += A x X ; wave owns cw in [32*wave, +32) ----
        #pragma unroll
        for (int mt2 = 0; mt2 < 2; ++mt2) {
            const int cwrow = wave * 32 + mt2 * 16 + l15;
            bf16x8 a0 = *reinterpret_cast<const bf16x8*>(&sAt[cwrow * ATP + quad * 8]);
            bf16x8 a1 = *reinterpret_cast<const bf16x8*>(&sAt[cwrow * ATP + 32 + quad * 8]);
            #pragma unroll
            for (int dt = 0; dt < 8; ++dt) {
                const int drow = dt * 16 + l15;
                const int sw = ((drow >> 3) & 3) << 3;
                const unsigned short* xp = &sXT[drow * XTP];
                bf16x8 b0 = *reinterpret_cast<const bf16x8*>(&xp[(quad * 8) ^ sw]);
                bf16x8 b1 = *reinterpret_cast<const bf16x8*>(&xp[(32 + quad * 8) ^ sw]);
                eacc[mt2][dt] = __builtin_amdgcn_mfma_f32_16x16x32_bf16(a0, b0, eacc[mt2][dt], 0, 0, 0);
                eacc[mt2][dt] = __builtin_amdgcn_mfma_f32_16x16x32_bf16(a1, b1, eacc[mt2][dt], 0, 0, 0);
            }
        }
    }

    // ---- counts: reduce over wave's 16 n-columns, publish per-wave to LDS ----
    #pragma unroll
    for (int mt = 0; mt < 8; ++mt) {
        #pragma unroll
        for (int r = 0; r < 4; ++r) {
            float c = cnt[mt][r];
            c += __shfl_xor(c, 1);
            c += __shfl_xor(c, 2);
            c += __shfl_xor(c, 4);
            c += __shfl_xor(c, 8);
            if (l15 == 0) sCntW[wave][mt * 16 + quad * 4 + r] = c;
        }
    }
    __syncthreads();

    // ---- epilogue: bf16 partial (E_part - count*C) to private ws slice ----
    unsigned short* P = Pg + (size_t)bid * (NK * ND);
    #pragma unroll
    for (int mt2 = 0; mt2 < 2; ++mt2) {
        #pragma unroll
        for (int r = 0; r < 4; ++r) {
            const int cw = wave * 32 + mt2 * 16 + quad * 4 + r;
            const float cc = sCntW[0][cw] + sCntW[1][cw] + sCntW[2][cw] + sCntW[3][cw];
            const float* crow = Cg + cw * ND;
            #pragma unroll
            for (int dt = 0; dt < 8; ++dt) {
                const int d = dt * 16 + l15;
                P[cw * ND + d] = f2bf(eacc[mt2][dt][r] - cc * crow[d]);
            }
        }
    }
}

// ---------------- kernel 3: partial reduction ----------------
__global__ __launch_bounds__(256) void vq_reduce(
    const unsigned short* __restrict__ Pg, float* __restrict__ Eg)
{
    const int g  = blockIdx.x * 256 + threadIdx.x;   // 0..32767
    const int b  = g >> 12;                          // 4096 quad-groups per b
    const int i4 = g & 4095;
    const unsigned short* base = Pg + (size_t)(b * BPB) * (NK * ND) + i4 * 4;
    float a0 = 0.f, a1 = 0.f, a2 = 0.f, a3 = 0.f;
    #pragma unroll 8
    for (int j = 0; j < BPB; ++j) {
        ushort4 v = *reinterpret_cast<const ushort4*>(base + (size_t)j * (NK * ND));
        a0 += bf2f(v.x); a1 += bf2f(v.y); a2 += bf2f(v.z); a3 += bf2f(v.w);
    }
    float4 o; o.x = a0; o.y = a1; o.z = a2; o.w = a3;
    *reinterpret_cast<float4*>(Eg + (size_t)b * (NK * ND) + i4 * 4) = o;
}

extern "C" void kernel_launch(void* const* d_in, const int* in_sizes, int n_in,
                              void* d_out, int out_size, void* d_ws, size_t ws_size,
                              hipStream_t stream) {
    const float* X = (const float*)d_in[0];
    const float* C = (const float*)d_in[1];
    const float* S = (const float*)d_in[2];
    float* E = (float*)d_out;
    (void)n_in; (void)in_sizes; (void)out_size; (void)ws_size;

    // ws layout: [0, 32MiB) bf16 partials; then bf16 C; then float2 ST.
    unsigned short* P   = (unsigned short*)d_ws;                       // 1024*16384 u16
    unsigned short* Cbf = (unsigned short*)((char*)d_ws + (size_t)8 * BPB * NK * ND * 2);
    float2*         ST  = (float2*)((char*)Cbf + (size_t)NK * ND * 2);

    hipLaunchKernelGGL(cprep,     dim3(1),    dim3(256), 0, stream, C, S, Cbf, ST);
    hipLaunchKernelGGL(vq_main,   dim3(1024), dim3(256), 0, stream, X, C, Cbf, ST, P);
    hipLaunchKernelGGL(vq_reduce, dim3(128),  dim3(256), 0, stream, P, E);
}

// Round 3
// 231.742 us; speedup vs baseline: 1.2548x; 1.2548x over previous
//
#include <hip/hip_runtime.h>

// Soft VQ encoding, fused bf16-MFMA implementation. Round 3.
//   X:(8,16384,128) fp32, C:(128,128) fp32, S:(128) fp32 -> E:(8,128,128) fp32
// Round-2 post-mortem: __launch_bounds__(256,4) capped regs at 128/wave ->
// ~40 regs of scratch SPILL in the hot loop -> +500MB HBM traffic (FETCH 257MB,
// WRITE 334MB), 204us. Fix: launch_bounds(256,3) (cap ~170, the 3-waves/SIMD
// breakpoint; round-1 proved 168 fits) + remove 32 live regs by computing
// codeword counts via a ones-column MFMA instead of cnt[8][4]+shuffles+LDS.
// 3 kernels on stream:
//   1. cprep<<<1,256>>>: C fp32->bf16 into ws; ST[k]={S[k],S[k]*C2[k]}.
//   2. vq_main<<<1024,256>>>: 8 b x 128 blk, TT=2 chunks of 64 rows. matmul1
//      (C x X^T) from global-bf16 C + in-reg X frags; softmax in C/D layout;
//      A,X^T via LDS; matmul2 (A^T x X) + ones-matmul for counts; bf16
//      partial (E_part - count*C) to private ws slice (no atomics).
//   3. vq_reduce<<<128,256>>>: fp32-sum 128 bf16 partials -> d_out.

#define NN   16384
#define ND   128
#define NK   128
#define NC   64        // rows per chunk
#define TT   2         // chunks per block
#define BPB  128       // blocks per batch (grid = 8*BPB = 1024)
#define XTP  72        // X^T LDS row stride, 144B
#define ATP  72        // A^T LDS row stride, 144B

typedef __bf16 bf16x8 __attribute__((ext_vector_type(8)));
typedef float  f32x4  __attribute__((ext_vector_type(4)));

__device__ __forceinline__ unsigned short f2bf(float x) {
    unsigned int u = __float_as_uint(x);
    u = (u + 0x7fffu + ((u >> 16) & 1u)) >> 16;   // round-to-nearest-even
    return (unsigned short)u;
}
__device__ __forceinline__ float bf2f(unsigned short u) {
    return __uint_as_float(((unsigned int)u) << 16);
}

// ---------------- kernel 1: C prep ----------------
__global__ void cprep(const float* __restrict__ Cg, const float* __restrict__ Sg,
                      unsigned short* __restrict__ Cbf, float2* __restrict__ ST)
{
    const int t = threadIdx.x;        // 256 threads
    const int r = t >> 1;             // row 0..127
    const int h = t & 1;              // half-row
    const float* row = Cg + r * ND + h * 64;
    unsigned short* orow = Cbf + r * ND + h * 64;
    float ss = 0.f;
    #pragma unroll
    for (int i = 0; i < 16; ++i) {
        float4 v = reinterpret_cast<const float4*>(row)[i];
        ss += v.x*v.x + v.y*v.y + v.z*v.z + v.w*v.w;
        ushort4 hh;
        hh.x = f2bf(v.x); hh.y = f2bf(v.y); hh.z = f2bf(v.z); hh.w = f2bf(v.w);
        reinterpret_cast<ushort4*>(orow)[i] = hh;
    }
    ss += __shfl_xor(ss, 1);          // combine the two half-rows (same wave)
    if (h == 0) {
        float s = Sg[r];
        ST[r] = make_float2(s, s * ss);
    }
}

// ---------------- kernel 2: fused main ----------------
__global__ __launch_bounds__(256, 3) void vq_main(
    const float* __restrict__ Xg, const float* __restrict__ Cg,
    const unsigned short* __restrict__ Cbf, const float2* __restrict__ STg,
    unsigned short* __restrict__ Pg)
{
    __shared__ __align__(16) unsigned short sXT[ND * XTP];   // 18432 B
    __shared__ __align__(16) unsigned short sAt[NK * ATP];   // 18432 B
    __shared__ __align__(16) float2 sST[NK];                 // 1 KB

    const int tid  = threadIdx.x;
    const int lane = tid & 63;
    const int wave = tid >> 6;
    const int l15  = lane & 15;
    const int quad = lane >> 4;
    const int bid  = blockIdx.x;
    const int b    = bid >> 7;        // batch
    const int bg   = bid & (BPB - 1); // block-in-batch

    if (tid < NK) sST[tid] = STg[tid];
    // (barrier (A) of chunk 0 orders sST before first softmax use)

    f32x4 eacc[2][8];
    #pragma unroll
    for (int i = 0; i < 2; ++i)
        #pragma unroll
        for (int j = 0; j < 8; ++j)
            eacc[i][j] = (f32x4){0.f, 0.f, 0.f, 0.f};
    f32x4 cntacc[2];
    cntacc[0] = (f32x4){0.f, 0.f, 0.f, 0.f};
    cntacc[1] = (f32x4){0.f, 0.f, 0.f, 0.f};

    union CU { unsigned short u[8]; bf16x8 v; };
    CU one8;
    #pragma unroll
    for (int j = 0; j < 8; ++j) one8.u[j] = 0x3F80;  // bf16 1.0

    const float* Xb = Xg + (size_t)b * (NN * ND);
    const int rloc = wave * 16 + l15;   // chunk-local row this lane stages

    #pragma unroll 1
    for (int t = 0; t < TT; ++t) {
        const int chunk = bg * TT + t;
        const float* rp = Xb + (size_t)(chunk * NC + rloc) * ND;

        // ---- load this wave's 16 rows as matmul1 B-fragments; fp32 X2 ----
        CU cu[4];
        float x2 = 0.f;
        #pragma unroll
        for (int ks = 0; ks < 4; ++ks) {
            float4 va = *reinterpret_cast<const float4*>(rp + ks * 32 + quad * 8);
            float4 vb = *reinterpret_cast<const float4*>(rp + ks * 32 + quad * 8 + 4);
            x2 += va.x*va.x + va.y*va.y + va.z*va.z + va.w*va.w;
            x2 += vb.x*vb.x + vb.y*vb.y + vb.z*vb.z + vb.w*vb.w;
            cu[ks].u[0] = f2bf(va.x); cu[ks].u[1] = f2bf(va.y);
            cu[ks].u[2] = f2bf(va.z); cu[ks].u[3] = f2bf(va.w);
            cu[ks].u[4] = f2bf(vb.x); cu[ks].u[5] = f2bf(vb.y);
            cu[ks].u[6] = f2bf(vb.z); cu[ks].u[7] = f2bf(vb.w);
        }
        x2 += __shfl_xor(x2, 16);
        x2 += __shfl_xor(x2, 32);       // full X2 of row (chunk*64 + rloc)

        __syncthreads();                // (A) prev chunk's matmul2 reads done

        // ---- scatter X^T (swizzled to dodge bank conflicts) ----
        #pragma unroll
        for (int ks = 0; ks < 4; ++ks) {
            #pragma unroll
            for (int j = 0; j < 8; ++j) {
                int d  = ks * 32 + quad * 8 + j;
                int rs = rloc ^ (((d >> 3) & 3) << 3);
                sXT[d * XTP + rs] = cu[ks].u[j];
            }
        }

        // ---- matmul1: DT[cw][n] = C x X^T (A-frags from global bf16 C, L2) ----
        f32x4 dacc[8];
        #pragma unroll
        for (int mt = 0; mt < 8; ++mt) {
            f32x4 acc = (f32x4){0.f, 0.f, 0.f, 0.f};
            #pragma unroll
            for (int ks = 0; ks < 4; ++ks) {
                bf16x8 af = *reinterpret_cast<const bf16x8*>(
                    &Cbf[(mt * 16 + l15) * ND + ks * 32 + quad * 8]);
                acc = __builtin_amdgcn_mfma_f32_16x16x32_bf16(af, cu[ks].v, acc, 0, 0, 0);
            }
            dacc[mt] = acc;
        }

        // ---- softmax over cw (lane's column n = rloc) ----
        float mx = -3.0e38f;
        #pragma unroll
        for (int mt = 0; mt < 8; ++mt) {
            #pragma unroll
            for (int r = 0; r < 4; ++r) {
                float2 st = sST[mt * 16 + quad * 4 + r];
                float dv = st.x * fmaf(-2.f, dacc[mt][r], x2) + st.y;  // S*(X2-2XC)+S*C2
                dacc[mt][r] = dv;
                mx = fmaxf(mx, dv);
            }
        }
        mx = fmaxf(mx, __shfl_xor(mx, 16));
        mx = fmaxf(mx, __shfl_xor(mx, 32));
        float ls = 0.f;
        #pragma unroll
        for (int mt = 0; mt < 8; ++mt) {
            #pragma unroll
            for (int r = 0; r < 4; ++r) {
                float e = __expf(dacc[mt][r] - mx);
                dacc[mt][r] = e;
                ls += e;
            }
        }
        ls += __shfl_xor(ls, 16);
        ls += __shfl_xor(ls, 32);
        const float inv = 1.0f / ls;

        // ---- A -> LDS (A-operand layout: rows=cw, cols=n) ----
        #pragma unroll
        for (int mt = 0; mt < 8; ++mt) {
            #pragma unroll
            for (int r = 0; r < 4; ++r) {
                float a = dacc[mt][r] * inv;
                sAt[(mt * 16 + quad * 4 + r) * ATP + rloc] = f2bf(a);
            }
        }

        __syncthreads();                // (B) X^T and A^T visible to all waves

        // ---- matmul2: E[cw][d] += A x X ; counts via ones-column MFMA ----
        #pragma unroll
        for (int mt2 = 0; mt2 < 2; ++mt2) {
            const int cwrow = wave * 32 + mt2 * 16 + l15;
            bf16x8 a0 = *reinterpret_cast<const bf16x8*>(&sAt[cwrow * ATP + quad * 8]);
            bf16x8 a1 = *reinterpret_cast<const bf16x8*>(&sAt[cwrow * ATP + 32 + quad * 8]);
            // count[cw] += sum_n A[cw][n]: B = ones -> D[row][col] indep of col
            cntacc[mt2] = __builtin_amdgcn_mfma_f32_16x16x32_bf16(a0, one8.v, cntacc[mt2], 0, 0, 0);
            cntacc[mt2] = __builtin_amdgcn_mfma_f32_16x16x32_bf16(a1, one8.v, cntacc[mt2], 0, 0, 0);
            #pragma unroll
            for (int dt = 0; dt < 8; ++dt) {
                const int drow = dt * 16 + l15;
                const int sw = ((drow >> 3) & 3) << 3;
                const unsigned short* xp = &sXT[drow * XTP];
                bf16x8 b0 = *reinterpret_cast<const bf16x8*>(&xp[(quad * 8) ^ sw]);
                bf16x8 b1 = *reinterpret_cast<const bf16x8*>(&xp[(32 + quad * 8) ^ sw]);
                eacc[mt2][dt] = __builtin_amdgcn_mfma_f32_16x16x32_bf16(a0, b0, eacc[mt2][dt], 0, 0, 0);
                eacc[mt2][dt] = __builtin_amdgcn_mfma_f32_16x16x32_bf16(a1, b1, eacc[mt2][dt], 0, 0, 0);
            }
        }
    }

    // ---- epilogue: bf16 partial (E_part - count*C) to private ws slice ----
    // cntacc[mt2][r] holds count for cw = wave*32+mt2*16+quad*4+r (all l15 lanes)
    unsigned short* P = Pg + (size_t)bid * (NK * ND);
    #pragma unroll
    for (int mt2 = 0; mt2 < 2; ++mt2) {
        #pragma unroll
        for (int r = 0; r < 4; ++r) {
            const int cw = wave * 32 + mt2 * 16 + quad * 4 + r;
            const float cc = cntacc[mt2][r];
            const float* crow = Cg + cw * ND;
            #pragma unroll
            for (int dt = 0; dt < 8; ++dt) {
                const int d = dt * 16 + l15;
                P[cw * ND + d] = f2bf(eacc[mt2][dt][r] - cc * crow[d]);
            }
        }
    }
}

// ---------------- kernel 3: partial reduction ----------------
__global__ __launch_bounds__(256) void vq_reduce(
    const unsigned short* __restrict__ Pg, float* __restrict__ Eg)
{
    const int g  = blockIdx.x * 256 + threadIdx.x;   // 0..32767
    const int b  = g >> 12;                          // 4096 quad-groups per b
    const int i4 = g & 4095;
    const unsigned short* base = Pg + (size_t)(b * BPB) * (NK * ND) + i4 * 4;
    float a0 = 0.f, a1 = 0.f, a2 = 0.f, a3 = 0.f;
    #pragma unroll 8
    for (int j = 0; j < BPB; ++j) {
        ushort4 v = *reinterpret_cast<const ushort4*>(base + (size_t)j * (NK * ND));
        a0 += bf2f(v.x); a1 += bf2f(v.y); a2 += bf2f(v.z); a3 += bf2f(v.w);
    }
    float4 o; o.x = a0; o.y = a1; o.z = a2; o.w = a3;
    *reinterpret_cast<float4*>(Eg + (size_t)b * (NK * ND) + i4 * 4) = o;
}

extern "C" void kernel_launch(void* const* d_in, const int* in_sizes, int n_in,
                              void* d_out, int out_size, void* d_ws, size_t ws_size,
                              hipStream_t stream) {
    const float* X = (const float*)d_in[0];
    const float* C = (const float*)d_in[1];
    const float* S = (const float*)d_in[2];
    float* E = (float*)d_out;
    (void)n_in; (void)in_sizes; (void)out_size; (void)ws_size;

    // ws layout: [0, 32MiB) bf16 partials; then bf16 C; then float2 ST.
    unsigned short* P   = (unsigned short*)d_ws;                       // 1024*16384 u16
    unsigned short* Cbf = (unsigned short*)((char*)d_ws + (size_t)8 * BPB * NK * ND * 2);
    float2*         ST  = (float2*)((char*)Cbf + (size_t)NK * ND * 2);

    hipLaunchKernelGGL(cprep,     dim3(1),    dim3(256), 0, stream, C, S, Cbf, ST);
    hipLaunchKernelGGL(vq_main,   dim3(1024), dim3(256), 0, stream, X, C, Cbf, ST, P);
    hipLaunchKernelGGL(vq_reduce, dim3(128),  dim3(256), 0, stream, P, E);
}

// Round 4
// 186.162 us; speedup vs baseline: 1.5620x; 1.2448x over previous
//
#include <hip/hip_runtime.h>

// Soft VQ encoding, fused bf16-MFMA implementation. Round 4.
//   X:(8,16384,128) fp32, C:(128,128) fp32, S:(128) fp32 -> E:(8,128,128) fp32
// Post-mortem history:
//   r1: no spill + contended fp32 atomics -> 104us (atomic tail ~110us model).
//   r2: launch_bounds(256,4) cap=128 regs -> ~40 slots spilled -> 204us.
//   r3: launch_bounds(256,3) cap=168 regs -> ~12 slots spilled in dependent
//       chains (FETCH +111MB, WRITE +149MB scratch) -> 144us.
// r4: launch_bounds(256,2) cap=256. r1 proved this structure fits in 168 regs
// (104 VGPR + 64 AGPR) with MORE live state than now -> expect zero spill AND
// no atomics for the first time. Everything else identical to r3.
// 3 kernels on stream:
//   1. cprep<<<1,256>>>: C fp32->bf16 into ws; ST[k]={S[k],S[k]*C2[k]}.
//   2. vq_main<<<1024,256>>>: 8 b x 128 blk, TT=2 chunks of 64 rows. matmul1
//      (C x X^T) from global-bf16 C + in-reg X frags; softmax in C/D layout;
//      A,X^T via LDS; matmul2 (A^T x X) + ones-matmul for counts; bf16
//      partial (E_part - count*C) to private ws slice (no atomics).
//   3. vq_reduce<<<128,256>>>: fp32-sum 128 bf16 partials -> d_out.

#define NN   16384
#define ND   128
#define NK   128
#define NC   64        // rows per chunk
#define TT   2         // chunks per block
#define BPB  128       // blocks per batch (grid = 8*BPB = 1024)
#define XTP  72        // X^T LDS row stride, 144B
#define ATP  72        // A^T LDS row stride, 144B

typedef __bf16 bf16x8 __attribute__((ext_vector_type(8)));
typedef float  f32x4  __attribute__((ext_vector_type(4)));

__device__ __forceinline__ unsigned short f2bf(float x) {
    unsigned int u = __float_as_uint(x);
    u = (u + 0x7fffu + ((u >> 16) & 1u)) >> 16;   // round-to-nearest-even
    return (unsigned short)u;
}
__device__ __forceinline__ float bf2f(unsigned short u) {
    return __uint_as_float(((unsigned int)u) << 16);
}

// ---------------- kernel 1: C prep ----------------
__global__ void cprep(const float* __restrict__ Cg, const float* __restrict__ Sg,
                      unsigned short* __restrict__ Cbf, float2* __restrict__ ST)
{
    const int t = threadIdx.x;        // 256 threads
    const int r = t >> 1;             // row 0..127
    const int h = t & 1;              // half-row
    const float* row = Cg + r * ND + h * 64;
    unsigned short* orow = Cbf + r * ND + h * 64;
    float ss = 0.f;
    #pragma unroll
    for (int i = 0; i < 16; ++i) {
        float4 v = reinterpret_cast<const float4*>(row)[i];
        ss += v.x*v.x + v.y*v.y + v.z*v.z + v.w*v.w;
        ushort4 hh;
        hh.x = f2bf(v.x); hh.y = f2bf(v.y); hh.z = f2bf(v.z); hh.w = f2bf(v.w);
        reinterpret_cast<ushort4*>(orow)[i] = hh;
    }
    ss += __shfl_xor(ss, 1);          // combine the two half-rows (same wave)
    if (h == 0) {
        float s = Sg[r];
        ST[r] = make_float2(s, s * ss);
    }
}

// ---------------- kernel 2: fused main ----------------
__global__ __launch_bounds__(256, 2) void vq_main(
    const float* __restrict__ Xg, const float* __restrict__ Cg,
    const unsigned short* __restrict__ Cbf, const float2* __restrict__ STg,
    unsigned short* __restrict__ Pg)
{
    __shared__ __align__(16) unsigned short sXT[ND * XTP];   // 18432 B
    __shared__ __align__(16) unsigned short sAt[NK * ATP];   // 18432 B
    __shared__ __align__(16) float2 sST[NK];                 // 1 KB

    const int tid  = threadIdx.x;
    const int lane = tid & 63;
    const int wave = tid >> 6;
    const int l15  = lane & 15;
    const int quad = lane >> 4;
    const int bid  = blockIdx.x;
    const int b    = bid >> 7;        // batch
    const int bg   = bid & (BPB - 1); // block-in-batch

    if (tid < NK) sST[tid] = STg[tid];
    // (barrier (A) of chunk 0 orders sST before first softmax use)

    f32x4 eacc[2][8];
    #pragma unroll
    for (int i = 0; i < 2; ++i)
        #pragma unroll
        for (int j = 0; j < 8; ++j)
            eacc[i][j] = (f32x4){0.f, 0.f, 0.f, 0.f};
    f32x4 cntacc[2];
    cntacc[0] = (f32x4){0.f, 0.f, 0.f, 0.f};
    cntacc[1] = (f32x4){0.f, 0.f, 0.f, 0.f};

    union CU { unsigned short u[8]; bf16x8 v; };
    CU one8;
    #pragma unroll
    for (int j = 0; j < 8; ++j) one8.u[j] = 0x3F80;  // bf16 1.0

    const float* Xb = Xg + (size_t)b * (NN * ND);
    const int rloc = wave * 16 + l15;   // chunk-local row this lane stages

    #pragma unroll 1
    for (int t = 0; t < TT; ++t) {
        const int chunk = bg * TT + t;
        const float* rp = Xb + (size_t)(chunk * NC + rloc) * ND;

        // ---- load this wave's 16 rows as matmul1 B-fragments; fp32 X2 ----
        CU cu[4];
        float x2 = 0.f;
        #pragma unroll
        for (int ks = 0; ks < 4; ++ks) {
            float4 va = *reinterpret_cast<const float4*>(rp + ks * 32 + quad * 8);
            float4 vb = *reinterpret_cast<const float4*>(rp + ks * 32 + quad * 8 + 4);
            x2 += va.x*va.x + va.y*va.y + va.z*va.z + va.w*va.w;
            x2 += vb.x*vb.x + vb.y*vb.y + vb.z*vb.z + vb.w*vb.w;
            cu[ks].u[0] = f2bf(va.x); cu[ks].u[1] = f2bf(va.y);
            cu[ks].u[2] = f2bf(va.z); cu[ks].u[3] = f2bf(va.w);
            cu[ks].u[4] = f2bf(vb.x); cu[ks].u[5] = f2bf(vb.y);
            cu[ks].u[6] = f2bf(vb.z); cu[ks].u[7] = f2bf(vb.w);
        }
        x2 += __shfl_xor(x2, 16);
        x2 += __shfl_xor(x2, 32);       // full X2 of row (chunk*64 + rloc)

        __syncthreads();                // (A) prev chunk's matmul2 reads done

        // ---- scatter X^T (swizzled to dodge bank conflicts) ----
        #pragma unroll
        for (int ks = 0; ks < 4; ++ks) {
            #pragma unroll
            for (int j = 0; j < 8; ++j) {
                int d  = ks * 32 + quad * 8 + j;
                int rs = rloc ^ (((d >> 3) & 3) << 3);
                sXT[d * XTP + rs] = cu[ks].u[j];
            }
        }

        // ---- matmul1: DT[cw][n] = C x X^T (A-frags from global bf16 C, L2) ----
        f32x4 dacc[8];
        #pragma unroll
        for (int mt = 0; mt < 8; ++mt) {
            f32x4 acc = (f32x4){0.f, 0.f, 0.f, 0.f};
            #pragma unroll
            for (int ks = 0; ks < 4; ++ks) {
                bf16x8 af = *reinterpret_cast<const bf16x8*>(
                    &Cbf[(mt * 16 + l15) * ND + ks * 32 + quad * 8]);
                acc = __builtin_amdgcn_mfma_f32_16x16x32_bf16(af, cu[ks].v, acc, 0, 0, 0);
            }
            dacc[mt] = acc;
        }

        // ---- softmax over cw (lane's column n = rloc) ----
        float mx = -3.0e38f;
        #pragma unroll
        for (int mt = 0; mt < 8; ++mt) {
            #pragma unroll
            for (int r = 0; r < 4; ++r) {
                float2 st = sST[mt * 16 + quad * 4 + r];
                float dv = st.x * fmaf(-2.f, dacc[mt][r], x2) + st.y;  // S*(X2-2XC)+S*C2
                dacc[mt][r] = dv;
                mx = fmaxf(mx, dv);
            }
        }
        mx = fmaxf(mx, __shfl_xor(mx, 16));
        mx = fmaxf(mx, __shfl_xor(mx, 32));
        float ls = 0.f;
        #pragma unroll
        for (int mt = 0; mt < 8; ++mt) {
            #pragma unroll
            for (int r = 0; r < 4; ++r) {
                float e = __expf(dacc[mt][r] - mx);
                dacc[mt][r] = e;
                ls += e;
            }
        }
        ls += __shfl_xor(ls, 16);
        ls += __shfl_xor(ls, 32);
        const float inv = 1.0f / ls;

        // ---- A -> LDS (A-operand layout: rows=cw, cols=n) ----
        #pragma unroll
        for (int mt = 0; mt < 8; ++mt) {
            #pragma unroll
            for (int r = 0; r < 4; ++r) {
                float a = dacc[mt][r] * inv;
                sAt[(mt * 16 + quad * 4 + r) * ATP + rloc] = f2bf(a);
            }
        }

        __syncthreads();                // (B) X^T and A^T visible to all waves

        // ---- matmul2: E[cw][d] += A x X ; counts via ones-column MFMA ----
        #pragma unroll
        for (int mt2 = 0; mt2 < 2; ++mt2) {
            const int cwrow = wave * 32 + mt2 * 16 + l15;
            bf16x8 a0 = *reinterpret_cast<const bf16x8*>(&sAt[cwrow * ATP + quad * 8]);
            bf16x8 a1 = *reinterpret_cast<const bf16x8*>(&sAt[cwrow * ATP + 32 + quad * 8]);
            // count[cw] += sum_n A[cw][n]: B = ones -> D[row][col] indep of col
            cntacc[mt2] = __builtin_amdgcn_mfma_f32_16x16x32_bf16(a0, one8.v, cntacc[mt2], 0, 0, 0);
            cntacc[mt2] = __builtin_amdgcn_mfma_f32_16x16x32_bf16(a1, one8.v, cntacc[mt2], 0, 0, 0);
            #pragma unroll
            for (int dt = 0; dt < 8; ++dt) {
                const int drow = dt * 16 + l15;
                const int sw = ((drow >> 3) & 3) << 3;
                const unsigned short* xp = &sXT[drow * XTP];
                bf16x8 b0 = *reinterpret_cast<const bf16x8*>(&xp[(quad * 8) ^ sw]);
                bf16x8 b1 = *reinterpret_cast<const bf16x8*>(&xp[(32 + quad * 8) ^ sw]);
                eacc[mt2][dt] = __builtin_amdgcn_mfma_f32_16x16x32_bf16(a0, b0, eacc[mt2][dt], 0, 0, 0);
                eacc[mt2][dt] = __builtin_amdgcn_mfma_f32_16x16x32_bf16(a1, b1, eacc[mt2][dt], 0, 0, 0);
            }
        }
    }

    // ---- epilogue: bf16 partial (E_part - count*C) to private ws slice ----
    // cntacc[mt2][r] holds count for cw = wave*32+mt2*16+quad*4+r (all l15 lanes)
    unsigned short* P = Pg + (size_t)bid * (NK * ND);
    #pragma unroll
    for (int mt2 = 0; mt2 < 2; ++mt2) {
        #pragma unroll
        for (int r = 0; r < 4; ++r) {
            const int cw = wave * 32 + mt2 * 16 + quad * 4 + r;
            const float cc = cntacc[mt2][r];
            const float* crow = Cg + cw * ND;
            #pragma unroll
            for (int dt = 0; dt < 8; ++dt) {
                const int d = dt * 16 + l15;
                P[cw * ND + d] = f2bf(eacc[mt2][dt][r] - cc * crow[d]);
            }
        }
    }
}

// ---------------- kernel 3: partial reduction ----------------
__global__ __launch_bounds__(256) void vq_reduce(
    const unsigned short* __restrict__ Pg, float* __restrict__ Eg)
{
    const int g  = blockIdx.x * 256 + threadIdx.x;   // 0..32767
    const int b  = g >> 12;                          // 4096 quad-groups per b
    const int i4 = g & 4095;
    const unsigned short* base = Pg + (size_t)(b * BPB) * (NK * ND) + i4 * 4;
    float a0 = 0.f, a1 = 0.f, a2 = 0.f, a3 = 0.f;
    #pragma unroll 8
    for (int j = 0; j < BPB; ++j) {
        ushort4 v = *reinterpret_cast<const ushort4*>(base + (size_t)j * (NK * ND));
        a0 += bf2f(v.x); a1 += bf2f(v.y); a2 += bf2f(v.z); a3 += bf2f(v.w);
    }
    float4 o; o.x = a0; o.y = a1; o.z = a2; o.w = a3;
    *reinterpret_cast<float4*>(Eg + (size_t)b * (NK * ND) + i4 * 4) = o;
}

extern "C" void kernel_launch(void* const* d_in, const int* in_sizes, int n_in,
                              void* d_out, int out_size, void* d_ws, size_t ws_size,
                              hipStream_t stream) {
    const float* X = (const float*)d_in[0];
    const float* C = (const float*)d_in[1];
    const float* S = (const float*)d_in[2];
    float* E = (float*)d_out;
    (void)n_in; (void)in_sizes; (void)out_size; (void)ws_size;

    // ws layout: [0, 32MiB) bf16 partials; then bf16 C; then float2 ST.
    unsigned short* P   = (unsigned short*)d_ws;                       // 1024*16384 u16
    unsigned short* Cbf = (unsigned short*)((char*)d_ws + (size_t)8 * BPB * NK * ND * 2);
    float2*         ST  = (float2*)((char*)Cbf + (size_t)NK * ND * 2);

    hipLaunchKernelGGL(cprep,     dim3(1),    dim3(256), 0, stream, C, S, Cbf, ST);
    hipLaunchKernelGGL(vq_main,   dim3(1024), dim3(256), 0, stream, X, C, Cbf, ST, P);
    hipLaunchKernelGGL(vq_reduce, dim3(128),  dim3(256), 0, stream, P, E);
}

// Round 5
// 136.863 us; speedup vs baseline: 2.1247x; 1.3602x over previous
//
#include <hip/hip_runtime.h>

// Soft VQ encoding, fused bf16-MFMA implementation. Round 5.
//   X:(8,16384,128) fp32, C:(128,128) fp32, S:(128) fp32 -> E:(8,128,128) fp32
// Post-mortem history:
//   r1: LDS-staged C, no spill (arch VGPR=104), contended fp32 atomics -> 104us.
//   r2-r4: C read from global (bf16 Cbf in ws) -> compiler hoists all 32
//     A-frag global loads across the mt loop -> arch pressure ~150. The
//     allocator splits the unified file cap/2 arch + cap/2 accum (reported
//     VGPR_Count = 64/84/128 at caps 128/168/256), so the arch side spills at
//     EVERY cap. r4: +61MB scratch write, +27MB scratch read, vq_main 96us
//     with all pipes <11% -- latency-bound on mid-chain scratch reloads.
// r5: matmul1 A-operand back to LDS-staged C (r1-proven clean allocation),
//     keep r4's partial-store epilogue + ones-count MFMA. cprep folds into
//     vq_main (C conversion + C2 + ST per block, L3-resident reads) -> 2
//     dispatches (each extra graph node costs ~10-15us per dur_us deltas).
// 2 kernels on stream:
//   1. vq_main<<<1024,256>>>, launch_bounds(256,2): 8 b x 128 blk, TT=2
//      chunks of 64 rows. Prologue stages C->bf16 LDS + computes ST.
//      Per chunk: X rows -> reg frags (+fp32 X2), X^T -> LDS (swizzled),
//      matmul1 (sCb x X^T) 16x16x32 bf16, softmax in C/D layout, A -> LDS,
//      matmul2 (A x X) + ones-MFMA counts; bf16 partial (E - cnt*C) to
//      private ws slice (no atomics, no contention).
//   2. vq_reduce<<<128,256>>>: fp32-sum 128 bf16 partials -> d_out.

#define NN   16384
#define ND   128
#define NK   128
#define NC   64        // rows per chunk
#define TT   2         // chunks per block
#define BPB  128       // blocks per batch (grid = 8*BPB = 1024)
#define CBP  136       // sCb row stride (bf16 elems), 272B -> b128-aligned, 2-way banks
#define XTP  72        // X^T LDS row stride, 144B
#define ATP  72        // A^T LDS row stride, 144B

typedef __bf16 bf16x8 __attribute__((ext_vector_type(8)));
typedef float  f32x4  __attribute__((ext_vector_type(4)));

__device__ __forceinline__ unsigned short f2bf(float x) {
    unsigned int u = __float_as_uint(x);
    u = (u + 0x7fffu + ((u >> 16) & 1u)) >> 16;   // round-to-nearest-even
    return (unsigned short)u;
}
__device__ __forceinline__ float bf2f(unsigned short u) {
    return __uint_as_float(((unsigned int)u) << 16);
}

// ---------------- kernel 1: fused main ----------------
__global__ __launch_bounds__(256, 2) void vq_main(
    const float* __restrict__ Xg, const float* __restrict__ Cg,
    const float* __restrict__ Sg, unsigned short* __restrict__ Pg)
{
    __shared__ __align__(16) unsigned short sCb[NK * CBP];   // 34816 B
    __shared__ __align__(16) unsigned short sXT[ND * XTP];   // 18432 B
    __shared__ __align__(16) unsigned short sAt[NK * ATP];   // 18432 B
    __shared__ __align__(16) float2 sST[NK];                 // 1 KB
    __shared__ __align__(16) float  sC2[NK];                 // 512 B

    const int tid  = threadIdx.x;
    const int lane = tid & 63;
    const int wave = tid >> 6;
    const int l15  = lane & 15;
    const int quad = lane >> 4;
    const int bid  = blockIdx.x;
    const int b    = bid >> 7;        // batch
    const int bg   = bid & (BPB - 1); // block-in-batch

    // ---- prologue: stage C -> bf16 LDS, C2 row sums, ST = {S, S*C2} ----
    #pragma unroll
    for (int it = 0; it < 16; ++it) {
        int flat = it * 256 + tid;
        int row  = flat >> 5;          // 0..127
        int c4   = flat & 31;
        float4 v = reinterpret_cast<const float4*>(Cg)[row * 32 + c4];
        ushort4 h;
        h.x = f2bf(v.x); h.y = f2bf(v.y); h.z = f2bf(v.z); h.w = f2bf(v.w);
        *reinterpret_cast<ushort4*>(&sCb[row * CBP + c4 * 4]) = h;
        float ss = v.x*v.x + v.y*v.y + v.z*v.z + v.w*v.w;
        ss += __shfl_xor(ss, 1);
        ss += __shfl_xor(ss, 2);
        ss += __shfl_xor(ss, 4);
        ss += __shfl_xor(ss, 8);
        ss += __shfl_xor(ss, 16);
        if ((lane & 31) == 0) sC2[row] = ss;
    }
    __syncthreads();
    if (tid < NK) {
        float s = Sg[tid];
        sST[tid] = make_float2(s, s * sC2[tid]);
    }
    // (barrier (A) of chunk 0 orders sST before first softmax use)

    f32x4 eacc[2][8];
    #pragma unroll
    for (int i = 0; i < 2; ++i)
        #pragma unroll
        for (int j = 0; j < 8; ++j)
            eacc[i][j] = (f32x4){0.f, 0.f, 0.f, 0.f};
    f32x4 cntacc[2];
    cntacc[0] = (f32x4){0.f, 0.f, 0.f, 0.f};
    cntacc[1] = (f32x4){0.f, 0.f, 0.f, 0.f};

    union CU { unsigned short u[8]; bf16x8 v; };
    CU one8;
    #pragma unroll
    for (int j = 0; j < 8; ++j) one8.u[j] = 0x3F80;  // bf16 1.0

    const float* Xb = Xg + (size_t)b * (NN * ND);
    const int rloc = wave * 16 + l15;   // chunk-local row this lane stages

    #pragma unroll 1
    for (int t = 0; t < TT; ++t) {
        const int chunk = bg * TT + t;
        const float* rp = Xb + (size_t)(chunk * NC + rloc) * ND;

        // ---- load this wave's 16 rows as matmul1 B-fragments; fp32 X2 ----
        CU cu[4];
        float x2 = 0.f;
        #pragma unroll
        for (int ks = 0; ks < 4; ++ks) {
            float4 va = *reinterpret_cast<const float4*>(rp + ks * 32 + quad * 8);
            float4 vb = *reinterpret_cast<const float4*>(rp + ks * 32 + quad * 8 + 4);
            x2 += va.x*va.x + va.y*va.y + va.z*va.z + va.w*va.w;
            x2 += vb.x*vb.x + vb.y*vb.y + vb.z*vb.z + vb.w*vb.w;
            cu[ks].u[0] = f2bf(va.x); cu[ks].u[1] = f2bf(va.y);
            cu[ks].u[2] = f2bf(va.z); cu[ks].u[3] = f2bf(va.w);
            cu[ks].u[4] = f2bf(vb.x); cu[ks].u[5] = f2bf(vb.y);
            cu[ks].u[6] = f2bf(vb.z); cu[ks].u[7] = f2bf(vb.w);
        }
        x2 += __shfl_xor(x2, 16);
        x2 += __shfl_xor(x2, 32);       // full X2 of row (chunk*64 + rloc)

        __syncthreads();                // (A) prev chunk's matmul2 reads done

        // ---- scatter X^T (swizzled to dodge bank conflicts) ----
        #pragma unroll
        for (int ks = 0; ks < 4; ++ks) {
            #pragma unroll
            for (int j = 0; j < 8; ++j) {
                int d  = ks * 32 + quad * 8 + j;
                int rs = rloc ^ (((d >> 3) & 3) << 3);
                sXT[d * XTP + rs] = cu[ks].u[j];
            }
        }

        // ---- matmul1: DT[cw][n] = C x X^T (A-frags from LDS sCb) ----
        f32x4 dacc[8];
        #pragma unroll
        for (int mt = 0; mt < 8; ++mt) {
            f32x4 acc = (f32x4){0.f, 0.f, 0.f, 0.f};
            #pragma unroll
            for (int ks = 0; ks < 4; ++ks) {
                bf16x8 af = *reinterpret_cast<const bf16x8*>(
                    &sCb[(mt * 16 + l15) * CBP + ks * 32 + quad * 8]);
                acc = __builtin_amdgcn_mfma_f32_16x16x32_bf16(af, cu[ks].v, acc, 0, 0, 0);
            }
            dacc[mt] = acc;
        }

        // ---- softmax over cw (lane's column n = rloc) ----
        float mx = -3.0e38f;
        #pragma unroll
        for (int mt = 0; mt < 8; ++mt) {
            #pragma unroll
            for (int r = 0; r < 4; ++r) {
                float2 st = sST[mt * 16 + quad * 4 + r];
                float dv = st.x * fmaf(-2.f, dacc[mt][r], x2) + st.y;  // S*(X2-2XC)+S*C2
                dacc[mt][r] = dv;
                mx = fmaxf(mx, dv);
            }
        }
        mx = fmaxf(mx, __shfl_xor(mx, 16));
        mx = fmaxf(mx, __shfl_xor(mx, 32));
        float ls = 0.f;
        #pragma unroll
        for (int mt = 0; mt < 8; ++mt) {
            #pragma unroll
            for (int r = 0; r < 4; ++r) {
                float e = __expf(dacc[mt][r] - mx);
                dacc[mt][r] = e;
                ls += e;
            }
        }
        ls += __shfl_xor(ls, 16);
        ls += __shfl_xor(ls, 32);
        const float inv = 1.0f / ls;

        // ---- A -> LDS (A-operand layout: rows=cw, cols=n) ----
        #pragma unroll
        for (int mt = 0; mt < 8; ++mt) {
            #pragma unroll
            for (int r = 0; r < 4; ++r) {
                float a = dacc[mt][r] * inv;
                sAt[(mt * 16 + quad * 4 + r) * ATP + rloc] = f2bf(a);
            }
        }

        __syncthreads();                // (B) X^T and A^T visible to all waves

        // ---- matmul2: E[cw][d] += A x X ; counts via ones-column MFMA ----
        #pragma unroll
        for (int mt2 = 0; mt2 < 2; ++mt2) {
            const int cwrow = wave * 32 + mt2 * 16 + l15;
            bf16x8 a0 = *reinterpret_cast<const bf16x8*>(&sAt[cwrow * ATP + quad * 8]);
            bf16x8 a1 = *reinterpret_cast<const bf16x8*>(&sAt[cwrow * ATP + 32 + quad * 8]);
            // count[cw] += sum_n A[cw][n]: B = ones -> D[row][col] indep of col
            cntacc[mt2] = __builtin_amdgcn_mfma_f32_16x16x32_bf16(a0, one8.v, cntacc[mt2], 0, 0, 0);
            cntacc[mt2] = __builtin_amdgcn_mfma_f32_16x16x32_bf16(a1, one8.v, cntacc[mt2], 0, 0, 0);
            #pragma unroll
            for (int dt = 0; dt < 8; ++dt) {
                const int drow = dt * 16 + l15;
                const int sw = ((drow >> 3) & 3) << 3;
                const unsigned short* xp = &sXT[drow * XTP];
                bf16x8 b0 = *reinterpret_cast<const bf16x8*>(&xp[(quad * 8) ^ sw]);
                bf16x8 b1 = *reinterpret_cast<const bf16x8*>(&xp[(32 + quad * 8) ^ sw]);
                eacc[mt2][dt] = __builtin_amdgcn_mfma_f32_16x16x32_bf16(a0, b0, eacc[mt2][dt], 0, 0, 0);
                eacc[mt2][dt] = __builtin_amdgcn_mfma_f32_16x16x32_bf16(a1, b1, eacc[mt2][dt], 0, 0, 0);
            }
        }
    }

    // ---- epilogue: bf16 partial (E_part - count*C) to private ws slice ----
    // cntacc[mt2][r] holds count for cw = wave*32+mt2*16+quad*4+r (all l15 lanes)
    unsigned short* P = Pg + (size_t)bid * (NK * ND);
    #pragma unroll
    for (int mt2 = 0; mt2 < 2; ++mt2) {
        #pragma unroll
        for (int r = 0; r < 4; ++r) {
            const int cw = wave * 32 + mt2 * 16 + quad * 4 + r;
            const float cc = cntacc[mt2][r];
            const float* crow = Cg + cw * ND;
            #pragma unroll
            for (int dt = 0; dt < 8; ++dt) {
                const int d = dt * 16 + l15;
                P[cw * ND + d] = f2bf(eacc[mt2][dt][r] - cc * crow[d]);
            }
        }
    }
}

// ---------------- kernel 2: partial reduction ----------------
__global__ __launch_bounds__(256) void vq_reduce(
    const unsigned short* __restrict__ Pg, float* __restrict__ Eg)
{
    const int g  = blockIdx.x * 256 + threadIdx.x;   // 0..32767
    const int b  = g >> 12;                          // 4096 quad-groups per b
    const int i4 = g & 4095;
    const unsigned short* base = Pg + (size_t)(b * BPB) * (NK * ND) + i4 * 4;
    float a0 = 0.f, a1 = 0.f, a2 = 0.f, a3 = 0.f;
    #pragma unroll 8
    for (int j = 0; j < BPB; ++j) {
        ushort4 v = *reinterpret_cast<const ushort4*>(base + (size_t)j * (NK * ND));
        a0 += bf2f(v.x); a1 += bf2f(v.y); a2 += bf2f(v.z); a3 += bf2f(v.w);
    }
    float4 o; o.x = a0; o.y = a1; o.z = a2; o.w = a3;
    *reinterpret_cast<float4*>(Eg + (size_t)b * (NK * ND) + i4 * 4) = o;
}

extern "C" void kernel_launch(void* const* d_in, const int* in_sizes, int n_in,
                              void* d_out, int out_size, void* d_ws, size_t ws_size,
                              hipStream_t stream) {
    const float* X = (const float*)d_in[0];
    const float* C = (const float*)d_in[1];
    const float* S = (const float*)d_in[2];
    float* E = (float*)d_out;
    (void)n_in; (void)in_sizes; (void)out_size; (void)ws_size;

    // ws layout: bf16 partials, 1024 * 16384 u16 = 32 MiB.
    unsigned short* P = (unsigned short*)d_ws;

    hipLaunchKernelGGL(vq_main,   dim3(1024), dim3(256), 0, stream, X, C, S, P);
    hipLaunchKernelGGL(vq_reduce, dim3(128),  dim3(256), 0, stream, P, E);
}

// Round 6
// 115.438 us; speedup vs baseline: 2.5191x; 1.1856x over previous
//
#include <hip/hip_runtime.h>

// Soft VQ encoding, fused bf16-MFMA implementation. Round 6.
//   X:(8,16384,128) fp32, C:(128,128) fp32, S:(128) fp32 -> E:(8,128,128) fp32
// r5 (55us main, clean traffic, VGPR=96) was latency-bound: all pipes <23%,
// 2 blocks/CU, serial chunk chain. r6 keeps the r5 skeleton and attacks the
// chain: (1) (__bf16) casts instead of manual integer RNE (v_cvt_pk_bf16_f32,
// was ~256 VALU/chunk); (2) TT=4/grid=512: prologue amortized over 4 chunks,
// P partials 16MB; (3) software-pipelined X loads: next chunk's first half
// issued right after barrier A, in flight across scatter/matmul1/softmax
// (+16 VGPR, est ~115 arch < 128 cap -- WRITE_SIZE>25MB = spill tripwire);
// (4) sST read as float4 pairs (16 b128 vs 32 b64 per chunk).
// 2 kernels on stream:
//   1. vq_main<<<512,256>>>, launch_bounds(256,2): 8 b x 64 blk, TT=4 chunks
//      of 64 rows. Prologue stages C->bf16 LDS + ST={S,S*C2}. Per chunk:
//      X rows -> reg frags (+fp32 X2), X^T -> LDS (swizzled), matmul1
//      (sCb x X^T) 16x16x32 bf16, softmax in C/D layout, A -> LDS, matmul2
//      (A x X) + ones-MFMA counts; bf16 partial (E - cnt*C) to private slice.
//   2. vq_reduce<<<128,256>>>: fp32-sum 64 bf16 partials -> d_out.

#define NN   16384
#define ND   128
#define NK   128
#define NC   64        // rows per chunk
#define TT   4         // chunks per block
#define BPB  64        // blocks per batch (grid = 8*BPB = 512)
#define CBP  136       // sCb row stride (bf16 elems), 272B -> b128-aligned, 2-way banks
#define XTP  72        // X^T LDS row stride, 144B
#define ATP  72        // A^T LDS row stride, 144B

typedef __bf16 bf16x8 __attribute__((ext_vector_type(8)));
typedef float  f32x4  __attribute__((ext_vector_type(4)));

union CU  { __bf16 b[8]; unsigned short u[8]; bf16x8 v; };
union HH4 { __bf16 b[4]; ushort4 s; };

__device__ __forceinline__ float bf2f(unsigned short u) {
    return __uint_as_float(((unsigned int)u) << 16);
}

// ---------------- kernel 1: fused main ----------------
__global__ __launch_bounds__(256, 2) void vq_main(
    const float* __restrict__ Xg, const float* __restrict__ Cg,
    const float* __restrict__ Sg, unsigned short* __restrict__ Pg)
{
    __shared__ __align__(16) unsigned short sCb[NK * CBP];   // 34816 B
    __shared__ __align__(16) unsigned short sXT[ND * XTP];   // 18432 B
    __shared__ __align__(16) unsigned short sAt[NK * ATP];   // 18432 B
    __shared__ __align__(16) float2 sST[NK];                 // 1 KB
    __shared__ __align__(16) float  sC2[NK];                 // 512 B

    const int tid  = threadIdx.x;
    const int lane = tid & 63;
    const int wave = tid >> 6;
    const int l15  = lane & 15;
    const int quad = lane >> 4;
    const int bid  = blockIdx.x;
    const int b    = bid >> 6;        // batch
    const int bg   = bid & (BPB - 1); // block-in-batch

    // ---- prologue: stage C -> bf16 LDS, C2 row sums, ST = {S, S*C2} ----
    #pragma unroll
    for (int it = 0; it < 16; ++it) {
        int flat = it * 256 + tid;
        int row  = flat >> 5;          // 0..127
        int c4   = flat & 31;
        float4 v = reinterpret_cast<const float4*>(Cg)[row * 32 + c4];
        HH4 h;
        h.b[0] = (__bf16)v.x; h.b[1] = (__bf16)v.y;
        h.b[2] = (__bf16)v.z; h.b[3] = (__bf16)v.w;
        *reinterpret_cast<ushort4*>(&sCb[row * CBP + c4 * 4]) = h.s;
        float ss = v.x*v.x + v.y*v.y + v.z*v.z + v.w*v.w;
        ss += __shfl_xor(ss, 1);
        ss += __shfl_xor(ss, 2);
        ss += __shfl_xor(ss, 4);
        ss += __shfl_xor(ss, 8);
        ss += __shfl_xor(ss, 16);
        if ((lane & 31) == 0) sC2[row] = ss;
    }
    __syncthreads();
    if (tid < NK) {
        float s = Sg[tid];
        sST[tid] = make_float2(s, s * sC2[tid]);
    }
    // (barrier (A) of chunk 0 orders sST before first softmax use)

    f32x4 eacc[2][8];
    #pragma unroll
    for (int i = 0; i < 2; ++i)
        #pragma unroll
        for (int j = 0; j < 8; ++j)
            eacc[i][j] = (f32x4){0.f, 0.f, 0.f, 0.f};
    f32x4 cntacc[2];
    cntacc[0] = (f32x4){0.f, 0.f, 0.f, 0.f};
    cntacc[1] = (f32x4){0.f, 0.f, 0.f, 0.f};

    CU one8;
    #pragma unroll
    for (int j = 0; j < 8; ++j) one8.u[j] = 0x3F80;  // bf16 1.0

    const float* Xb = Xg + (size_t)b * (NN * ND);
    const int rloc = wave * 16 + l15;   // chunk-local row this lane stages

    // software pipeline: raw[] holds next chunk's ks=0,1 halves (4 float4)
    float4 raw[4];
    {
        const float* rp0 = Xb + (size_t)(bg * TT * NC + rloc) * ND;
        raw[0] = *reinterpret_cast<const float4*>(rp0 + quad * 8);
        raw[1] = *reinterpret_cast<const float4*>(rp0 + quad * 8 + 4);
        raw[2] = *reinterpret_cast<const float4*>(rp0 + 32 + quad * 8);
        raw[3] = *reinterpret_cast<const float4*>(rp0 + 32 + quad * 8 + 4);
    }

    #pragma unroll 1
    for (int t = 0; t < TT; ++t) {
        const int chunk = bg * TT + t;
        const float* rp = Xb + (size_t)(chunk * NC + rloc) * ND;

        // ---- ks=2,3 loads issued first (latency overlapped w/ conversions) ----
        float4 va2 = *reinterpret_cast<const float4*>(rp + 64 + quad * 8);
        float4 vb2 = *reinterpret_cast<const float4*>(rp + 64 + quad * 8 + 4);
        float4 va3 = *reinterpret_cast<const float4*>(rp + 96 + quad * 8);
        float4 vb3 = *reinterpret_cast<const float4*>(rp + 96 + quad * 8 + 4);

        CU cu[4];
        float x2 = 0.f;
        #pragma unroll
        for (int ks = 0; ks < 2; ++ks) {
            float4 va = raw[ks * 2], vb = raw[ks * 2 + 1];
            x2 += va.x*va.x + va.y*va.y + va.z*va.z + va.w*va.w;
            x2 += vb.x*vb.x + vb.y*vb.y + vb.z*vb.z + vb.w*vb.w;
            cu[ks].b[0] = (__bf16)va.x; cu[ks].b[1] = (__bf16)va.y;
            cu[ks].b[2] = (__bf16)va.z; cu[ks].b[3] = (__bf16)va.w;
            cu[ks].b[4] = (__bf16)vb.x; cu[ks].b[5] = (__bf16)vb.y;
            cu[ks].b[6] = (__bf16)vb.z; cu[ks].b[7] = (__bf16)vb.w;
        }
        {
            x2 += va2.x*va2.x + va2.y*va2.y + va2.z*va2.z + va2.w*va2.w;
            x2 += vb2.x*vb2.x + vb2.y*vb2.y + vb2.z*vb2.z + vb2.w*vb2.w;
            cu[2].b[0] = (__bf16)va2.x; cu[2].b[1] = (__bf16)va2.y;
            cu[2].b[2] = (__bf16)va2.z; cu[2].b[3] = (__bf16)va2.w;
            cu[2].b[4] = (__bf16)vb2.x; cu[2].b[5] = (__bf16)vb2.y;
            cu[2].b[6] = (__bf16)vb2.z; cu[2].b[7] = (__bf16)vb2.w;
            x2 += va3.x*va3.x + va3.y*va3.y + va3.z*va3.z + va3.w*va3.w;
            x2 += vb3.x*vb3.x + vb3.y*vb3.y + vb3.z*vb3.z + vb3.w*vb3.w;
            cu[3].b[0] = (__bf16)va3.x; cu[3].b[1] = (__bf16)va3.y;
            cu[3].b[2] = (__bf16)va3.z; cu[3].b[3] = (__bf16)va3.w;
            cu[3].b[4] = (__bf16)vb3.x; cu[3].b[5] = (__bf16)vb3.y;
            cu[3].b[6] = (__bf16)vb3.z; cu[3].b[7] = (__bf16)vb3.w;
        }
        x2 += __shfl_xor(x2, 16);
        x2 += __shfl_xor(x2, 32);       // full X2 of row (chunk*64 + rloc)

        __syncthreads();                // (A) prev chunk's matmul2 reads done

        // ---- prefetch next chunk's ks=0,1 (in flight until barrier B) ----
        if (t + 1 < TT) {
            const float* rpn = rp + (size_t)NC * ND;
            raw[0] = *reinterpret_cast<const float4*>(rpn + quad * 8);
            raw[1] = *reinterpret_cast<const float4*>(rpn + quad * 8 + 4);
            raw[2] = *reinterpret_cast<const float4*>(rpn + 32 + quad * 8);
            raw[3] = *reinterpret_cast<const float4*>(rpn + 32 + quad * 8 + 4);
        }

        // ---- scatter X^T (swizzled to dodge bank conflicts) ----
        #pragma unroll
        for (int ks = 0; ks < 4; ++ks) {
            #pragma unroll
            for (int j = 0; j < 8; ++j) {
                int d  = ks * 32 + quad * 8 + j;
                int rs = rloc ^ (((d >> 3) & 3) << 3);
                sXT[d * XTP + rs] = cu[ks].u[j];
            }
        }

        // ---- matmul1: DT[cw][n] = C x X^T (A-frags from LDS sCb) ----
        f32x4 dacc[8];
        #pragma unroll
        for (int mt = 0; mt < 8; ++mt) {
            f32x4 acc = (f32x4){0.f, 0.f, 0.f, 0.f};
            #pragma unroll
            for (int ks = 0; ks < 4; ++ks) {
                bf16x8 af = *reinterpret_cast<const bf16x8*>(
                    &sCb[(mt * 16 + l15) * CBP + ks * 32 + quad * 8]);
                acc = __builtin_amdgcn_mfma_f32_16x16x32_bf16(af, cu[ks].v, acc, 0, 0, 0);
            }
            dacc[mt] = acc;
        }

        // ---- softmax over cw (lane's column n = rloc) ----
        float mx = -3.0e38f;
        #pragma unroll
        for (int mt = 0; mt < 8; ++mt) {
            // sST[mt*16+quad*4 .. +3] as two float4s: {S,SC2,S,SC2}
            float4 s01 = *reinterpret_cast<const float4*>(&sST[mt * 16 + quad * 4]);
            float4 s23 = *reinterpret_cast<const float4*>(&sST[mt * 16 + quad * 4 + 2]);
            float dv0 = s01.x * fmaf(-2.f, dacc[mt][0], x2) + s01.y;
            float dv1 = s01.z * fmaf(-2.f, dacc[mt][1], x2) + s01.w;
            float dv2 = s23.x * fmaf(-2.f, dacc[mt][2], x2) + s23.y;
            float dv3 = s23.z * fmaf(-2.f, dacc[mt][3], x2) + s23.w;
            dacc[mt][0] = dv0; dacc[mt][1] = dv1;
            dacc[mt][2] = dv2; dacc[mt][3] = dv3;
            mx = fmaxf(mx, fmaxf(fmaxf(dv0, dv1), fmaxf(dv2, dv3)));
        }
        mx = fmaxf(mx, __shfl_xor(mx, 16));
        mx = fmaxf(mx, __shfl_xor(mx, 32));
        float ls = 0.f;
        #pragma unroll
        for (int mt = 0; mt < 8; ++mt) {
            #pragma unroll
            for (int r = 0; r < 4; ++r) {
                float e = __expf(dacc[mt][r] - mx);
                dacc[mt][r] = e;
                ls += e;
            }
        }
        ls += __shfl_xor(ls, 16);
        ls += __shfl_xor(ls, 32);
        const float inv = 1.0f / ls;

        // ---- A -> LDS (A-operand layout: rows=cw, cols=n) ----
        #pragma unroll
        for (int mt = 0; mt < 8; ++mt) {
            #pragma unroll
            for (int r = 0; r < 4; ++r) {
                float a = dacc[mt][r] * inv;
                *reinterpret_cast<__bf16*>(
                    &sAt[(mt * 16 + quad * 4 + r) * ATP + rloc]) = (__bf16)a;
            }
        }

        __syncthreads();                // (B) X^T and A^T visible to all waves

        // ---- matmul2: E[cw][d] += A x X ; counts via ones-column MFMA ----
        #pragma unroll
        for (int mt2 = 0; mt2 < 2; ++mt2) {
            const int cwrow = wave * 32 + mt2 * 16 + l15;
            bf16x8 a0 = *reinterpret_cast<const bf16x8*>(&sAt[cwrow * ATP + quad * 8]);
            bf16x8 a1 = *reinterpret_cast<const bf16x8*>(&sAt[cwrow * ATP + 32 + quad * 8]);
            // count[cw] += sum_n A[cw][n]: B = ones -> D[row][col] indep of col
            cntacc[mt2] = __builtin_amdgcn_mfma_f32_16x16x32_bf16(a0, one8.v, cntacc[mt2], 0, 0, 0);
            cntacc[mt2] = __builtin_amdgcn_mfma_f32_16x16x32_bf16(a1, one8.v, cntacc[mt2], 0, 0, 0);
            #pragma unroll
            for (int dt = 0; dt < 8; ++dt) {
                const int drow = dt * 16 + l15;
                const int sw = ((drow >> 3) & 3) << 3;
                const unsigned short* xp = &sXT[drow * XTP];
                bf16x8 b0 = *reinterpret_cast<const bf16x8*>(&xp[(quad * 8) ^ sw]);
                bf16x8 b1 = *reinterpret_cast<const bf16x8*>(&xp[(32 + quad * 8) ^ sw]);
                eacc[mt2][dt] = __builtin_amdgcn_mfma_f32_16x16x32_bf16(a0, b0, eacc[mt2][dt], 0, 0, 0);
                eacc[mt2][dt] = __builtin_amdgcn_mfma_f32_16x16x32_bf16(a1, b1, eacc[mt2][dt], 0, 0, 0);
            }
        }
    }

    // ---- epilogue: bf16 partial (E_part - count*C) to private ws slice ----
    // cntacc[mt2][r] holds count for cw = wave*32+mt2*16+quad*4+r (all l15 lanes)
    unsigned short* P = Pg + (size_t)bid * (NK * ND);
    #pragma unroll
    for (int mt2 = 0; mt2 < 2; ++mt2) {
        #pragma unroll
        for (int r = 0; r < 4; ++r) {
            const int cw = wave * 32 + mt2 * 16 + quad * 4 + r;
            const float cc = cntacc[mt2][r];
            const float* crow = Cg + cw * ND;
            #pragma unroll
            for (int dt = 0; dt < 8; ++dt) {
                const int d = dt * 16 + l15;
                *reinterpret_cast<__bf16*>(&P[cw * ND + d]) =
                    (__bf16)(eacc[mt2][dt][r] - cc * crow[d]);
            }
        }
    }
}

// ---------------- kernel 2: partial reduction ----------------
__global__ __launch_bounds__(256) void vq_reduce(
    const unsigned short* __restrict__ Pg, float* __restrict__ Eg)
{
    const int g  = blockIdx.x * 256 + threadIdx.x;   // 0..32767
    const int b  = g >> 12;                          // 4096 quad-groups per b
    const int i4 = g & 4095;
    const unsigned short* base = Pg + (size_t)(b * BPB) * (NK * ND) + i4 * 4;
    float a0 = 0.f, a1 = 0.f, a2 = 0.f, a3 = 0.f;
    #pragma unroll 8
    for (int j = 0; j < BPB; ++j) {
        ushort4 v = *reinterpret_cast<const ushort4*>(base + (size_t)j * (NK * ND));
        a0 += bf2f(v.x); a1 += bf2f(v.y); a2 += bf2f(v.z); a3 += bf2f(v.w);
    }
    float4 o; o.x = a0; o.y = a1; o.z = a2; o.w = a3;
    *reinterpret_cast<float4*>(Eg + (size_t)b * (NK * ND) + i4 * 4) = o;
}

extern "C" void kernel_launch(void* const* d_in, const int* in_sizes, int n_in,
                              void* d_out, int out_size, void* d_ws, size_t ws_size,
                              hipStream_t stream) {
    const float* X = (const float*)d_in[0];
    const float* C = (const float*)d_in[1];
    const float* S = (const float*)d_in[2];
    float* E = (float*)d_out;
    (void)n_in; (void)in_sizes; (void)out_size; (void)ws_size;

    // ws layout: bf16 partials, 512 * 16384 u16 = 16 MiB.
    unsigned short* P = (unsigned short*)d_ws;

    hipLaunchKernelGGL(vq_main,   dim3(512), dim3(256), 0, stream, X, C, S, P);
    hipLaunchKernelGGL(vq_reduce, dim3(128), dim3(256), 0, stream, P, E);
}